// Round 14
// baseline (96.908 us; speedup 1.0000x reference)
//
#include <hip/hip_runtime.h>
#include <hip/hip_bf16.h>
#include <math.h>

#define TOK_TOTAL 16384
#define D_MODEL   2048
#define NEXP      64
#define BM        32               // tokens per block
#define KC        256              // k per chunk (1 KB per row per visit)
#define NCH       (D_MODEL / KC)   // 8
#define PADS      264              // shorts per LDS row (528 B, bank-balanced)
#define NBLK      (TOK_TOTAL / BM) // 512
#define TAU       1e-3f

#define IDX_OFF   (TOK_TOTAL * NEXP)
#define LOSS_OFF  (IDX_OFF + TOK_TOTAL * 2)

// ws (floats): WH8 [65536] | WL8 [65536] | cntp [512*64] | rep_cnt | rep_list
#define WS_WL     65536
#define WS_CNTP   (2 * 65536)
#define WS_RCNT   (WS_CNTP + NBLK * NEXP)
#define WS_RLIST  (WS_RCNT + 1)

typedef __attribute__((ext_vector_type(8))) short short8_t;
typedef __attribute__((ext_vector_type(4))) float f32x4;

__device__ __forceinline__ short cvh(float f) {
    return __builtin_bit_cast(short, __float2bfloat16(f));
}
__device__ __forceinline__ short cvl(float f) {
    __hip_bfloat16 h = __float2bfloat16(f);
    return __builtin_bit_cast(short, __float2bfloat16(f - __bfloat162float(h)));
}

// ---- K0: split-bf16 W table, k8-major: WH8[k8][e] = bf16hi(W[e][8k8..+7]) ----
__global__ __launch_bounds__(256, 1)
void build_wt(const float* __restrict__ W, short8_t* __restrict__ WH8,
              short8_t* __restrict__ WL8, int* __restrict__ rep_cnt)
{
    const int id = blockIdx.x * 256 + threadIdx.x;   // 64 blocks -> 16384 entries
    if (id == 0) *rep_cnt = 0;
    const int k8 = id & 255, e = id >> 8;
    float4 a = *(const float4*)(W + (long)e * D_MODEL + k8 * 8);
    float4 b = *(const float4*)(W + (long)e * D_MODEL + k8 * 8 + 4);
    short8_t h8, l8;
    h8[0]=cvh(a.x); h8[1]=cvh(a.y); h8[2]=cvh(a.z); h8[3]=cvh(a.w);
    h8[4]=cvh(b.x); h8[5]=cvh(b.y); h8[6]=cvh(b.z); h8[7]=cvh(b.w);
    l8[0]=cvl(a.x); l8[1]=cvl(a.y); l8[2]=cvl(a.z); l8[3]=cvl(a.w);
    l8[4]=cvl(b.x); l8[5]=cvl(b.y); l8[6]=cvl(b.z); l8[7]=cvl(b.w);
    WH8[k8 * NEXP + e] = h8;
    WL8[k8 * NEXP + e] = l8;
}

// ---- K1: fused GEMM (fat-burst x staging) + top-2/gates/flags/counts --------
__global__ __launch_bounds__(256, 2)
void router_gemm(const float* __restrict__ x,
                 const short8_t* __restrict__ WH8, const short8_t* __restrict__ WL8,
                 float* __restrict__ out, float* __restrict__ cntp,
                 int* __restrict__ rep_cnt, int* __restrict__ rep_list)
{
    __shared__ __align__(16) short sx[2][2][BM][PADS];   // [buf][h/l][row][col] 67.6 KB
    __shared__ float4 s_ig[BM];

    const int t  = threadIdx.x;
    const int w  = t >> 6, l = t & 63;
    const int tg = w >> 1, eg = w & 1;       // wave: tokens tg*16.., experts eg*32..
    const int lane16 = l & 15, kq = l >> 4;
    const long tok0 = (long)blockIdx.x * BM;

    const int srow = t >> 3;                 // staging row 0..31
    const int sseg = t & 7;                  // staging segment

    f32x4 acc0 = (f32x4){0.f,0.f,0.f,0.f};  // experts eg*32 + 0..15
    f32x4 acc1 = (f32x4){0.f,0.f,0.f,0.f};  // experts eg*32 + 16..31

    float4 xr[8];

    auto LOADX = [&](int c) {
        const float* g = x + (tok0 + srow) * D_MODEL + c * KC + sseg * 4;
        #pragma unroll
        for (int j = 0; j < 8; ++j) xr[j] = *(const float4*)(g + j * 32);
    };
    auto STOREX = [&](int buf) {
        #pragma unroll
        for (int j = 0; j < 8; ++j) {
            short4 h, lo;
            h.x = cvh(xr[j].x); h.y = cvh(xr[j].y); h.z = cvh(xr[j].z); h.w = cvh(xr[j].w);
            lo.x = cvl(xr[j].x); lo.y = cvl(xr[j].y); lo.z = cvl(xr[j].z); lo.w = cvl(xr[j].w);
            *(short4*)(&sx[buf][0][srow][sseg * 4 + j * 32]) = h;
            *(short4*)(&sx[buf][1][srow][sseg * 4 + j * 32]) = lo;
        }
    };

    // W fragment base for this lane (k8 = c*32 + g*4 + kq, expert eg*32 + nt*16 + lane16)
    const short8_t* whk = WH8 + (long)kq * NEXP + eg * 32 + lane16;
    const short8_t* wlk = WL8 + (long)kq * NEXP + eg * 32 + lane16;
    const int arow = tg * 16 + lane16;

    LOADX(0);
    STOREX(0);
    __syncthreads();

    for (int c = 0; c < NCH; ++c) {
        const int buf = c & 1;
        const bool pre = (c + 1 < NCH);
        if (pre) LOADX(c + 1);                    // issue early (T14)
        #pragma unroll
        for (int g = 0; g < 8; ++g) {
            short8_t ah = *(const short8_t*)(&sx[buf][0][arow][g * 32 + kq * 8]);
            short8_t al = *(const short8_t*)(&sx[buf][1][arow][g * 32 + kq * 8]);
            const long k8off = (long)(c * 32 + g * 4) * NEXP;
            short8_t bh0 = whk[k8off];
            short8_t bl0 = wlk[k8off];
            short8_t bh1 = whk[k8off + 16];
            short8_t bl1 = wlk[k8off + 16];
            acc0 = __builtin_amdgcn_mfma_f32_16x16x32_bf16(ah, bl0, acc0, 0, 0, 0);
            acc0 = __builtin_amdgcn_mfma_f32_16x16x32_bf16(al, bh0, acc0, 0, 0, 0);
            acc0 = __builtin_amdgcn_mfma_f32_16x16x32_bf16(ah, bh0, acc0, 0, 0, 0);
            acc1 = __builtin_amdgcn_mfma_f32_16x16x32_bf16(ah, bl1, acc1, 0, 0, 0);
            acc1 = __builtin_amdgcn_mfma_f32_16x16x32_bf16(al, bh1, acc1, 0, 0, 0);
            acc1 = __builtin_amdgcn_mfma_f32_16x16x32_bf16(ah, bh1, acc1, 0, 0, 0);
        }
        if (pre) STOREX(buf ^ 1);                 // write-late into other buffer
        __syncthreads();                          // one barrier per chunk
    }

    // ---- logits -> LDS (alias buf region; safe after final barrier) ----
    float* Lg = (float*)&sx[0][0][0][0];          // [32][68]
    {
        const int trow = tg * 16 + kq * 4;        // C-layout: row=(l>>4)*4+r, col=l&15
        #pragma unroll
        for (int r = 0; r < 4; ++r) {
            Lg[(trow + r) * 68 + eg * 32 + lane16]      = acc0[r];
            Lg[(trow + r) * 68 + eg * 32 + 16 + lane16] = acc1[r];
        }
    }
    __syncthreads();

    // ---- top-3, idx, flags ----
    if (t < BM) {
        const float* lrow = Lg + t * 68;
        float b0 = -1e30f, b1 = -1e30f, b2 = -1e30f;
        int i0 = 0, i1 = 0;
        for (int e = 0; e < NEXP; ++e) {
            float v = lrow[e];
            if (v > b0)      { b2 = b1; b1 = b0; i1 = i0; b0 = v; i0 = e; }
            else if (v > b1) { b2 = b1; b1 = v; i1 = e; }
            else if (v > b2) { b2 = v; }
        }
        float ex = __expf(b1 - b0);
        float g0 = 1.f / (1.f + ex);
        long tok = tok0 + t;
        out[IDX_OFF + 2 * tok]     = (float)i0;
        out[IDX_OFF + 2 * tok + 1] = (float)i1;
        s_ig[t] = make_float4((float)i0, (float)i1, g0, ex * g0);
        if ((b0 - b1 < TAU) || (b1 - b2 < TAU)) {
            int p = atomicAdd(rep_cnt, 1);
            rep_list[p] = (int)tok;
        }
    }
    __syncthreads();

    // ---- dense gates: 8 lanes per token, 8 floats each ----
    {
        const int r8 = t >> 3, e0 = (t & 7) * 8;
        float4 gg = s_ig[r8];
        const int i0 = (int)gg.x, i1 = (int)gg.y;
        float v[8];
        #pragma unroll
        for (int j = 0; j < 8; ++j) {
            int e = e0 + j;
            v[j] = (e == i0) ? gg.z : ((e == i1) ? gg.w : 0.f);
        }
        float* orow = out + (tok0 + r8) * NEXP + e0;
        *(float4*)(orow)     = make_float4(v[0], v[1], v[2], v[3]);
        *(float4*)(orow + 4) = make_float4(v[4], v[5], v[6], v[7]);
    }

    // ---- per-block expert counts ----
    if (t < NEXP) {
        float cs = 0.f;
        for (int tt = 0; tt < BM; ++tt) {
            float4 gg = s_ig[tt];
            if ((int)gg.x == t) cs += gg.z;
            if ((int)gg.y == t) cs += gg.w;
        }
        cntp[blockIdx.x * NEXP + t] = cs;
    }
}

// -------- K2: fused tail: block 0 = loss; blocks 1.. = fp64 index repair ------
__global__ __launch_bounds__(256, 1)
void router_tail(const float* __restrict__ x, const float* __restrict__ W,
                 float* __restrict__ out, const float* __restrict__ cntp,
                 const int* __restrict__ rep_cnt, const int* __restrict__ rep_list)
{
    const int t = threadIdx.x;

    if (blockIdx.x == 0) {
        __shared__ double red[4][NEXP];
        const int e = t & 63, p = t >> 6;
        double s = 0.0;
        for (int b = 0; b < NBLK / 4; ++b)
            s += (double)cntp[(p * (NBLK / 4) + b) * NEXP + e];
        red[p][e] = s;
        __syncthreads();
        if (t == 0) {
            double sc[NEXP], tot = 0.0;
            for (int i = 0; i < NEXP; ++i) {
                sc[i] = red[0][i] + red[1][i] + red[2][i] + red[3][i];
                tot += sc[i];
            }
            double loss = 0.0;
            for (int i = 0; i < NEXP; ++i) {
                double d = sc[i] / tot * (double)NEXP - 1.0;
                loss += d * d;
            }
            out[LOSS_OFF] = (float)(loss / NEXP);
        }
        return;
    }

    __shared__ double red[4][NEXP];
    const int nf = *rep_cnt;
    const int e = t & 63, part = t >> 6;
    for (int i = (int)blockIdx.x - 1; i < nf; i += (int)gridDim.x - 1) {
        const long tok = rep_list[i];
        const float* xr = x + tok * D_MODEL;
        const float* wr = W + (long)e * D_MODEL;
        const int k0 = part * 512;
        double s = 0.0;
        for (int kk = 0; kk < 512; kk += 4) {
            float4 xv = *(const float4*)(xr + k0 + kk);
            float4 wv = *(const float4*)(wr + k0 + kk);
            s = fma((double)xv.x, (double)wv.x, s);
            s = fma((double)xv.y, (double)wv.y, s);
            s = fma((double)xv.z, (double)wv.z, s);
            s = fma((double)xv.w, (double)wv.w, s);
        }
        red[part][e] = s;
        __syncthreads();
        if (t == 0) {
            double best = -1e300, sec = -1e300;
            int bi = 0, si = 0;
            for (int ee = 0; ee < NEXP; ++ee) {
                double vv = red[0][ee] + red[1][ee] + red[2][ee] + red[3][ee];
                if (vv > best)     { sec = best; si = bi; best = vv; bi = ee; }
                else if (vv > sec) { sec = vv; si = ee; }
            }
            out[IDX_OFF + 2 * tok]     = (float)bi;
            out[IDX_OFF + 2 * tok + 1] = (float)si;
        }
        __syncthreads();
    }
}

extern "C" void kernel_launch(void* const* d_in, const int* in_sizes, int n_in,
                              void* d_out, int out_size, void* d_ws, size_t ws_size,
                              hipStream_t stream)
{
    const float* x = (const float*)d_in[0];
    const float* W = (const float*)d_in[1];
    float* out = (float*)d_out;
    float* ws  = (float*)d_ws;         // ~720 KB used
    short8_t* WH8 = (short8_t*)ws;
    short8_t* WL8 = (short8_t*)(ws + WS_WL);
    float* cntp = ws + WS_CNTP;
    int* rep_cnt  = (int*)(ws + WS_RCNT);
    int* rep_list = (int*)(ws + WS_RLIST);

    build_wt   <<<64, 256, 0, stream>>>(W, WH8, WL8, rep_cnt);
    router_gemm<<<NBLK, 256, 0, stream>>>(x, WH8, WL8, out, cntp, rep_cnt, rep_list);
    router_tail<<<257, 256, 0, stream>>>(x, W, out, cntp, rep_cnt, rep_list);
}

// Round 15
// 89.607 us; speedup vs baseline: 1.0815x; 1.0815x over previous
//
#include <hip/hip_runtime.h>
#include <hip/hip_bf16.h>
#include <math.h>

#define TOK_TOTAL 16384
#define D_MODEL   2048
#define NEXP      64
#define BM        32               // tokens per block
#define KC        64               // k per chunk
#define NCH       (D_MODEL / KC)   // 32
#define NBLK      (TOK_TOTAL / BM) // 512
#define TAU       1e-3f

#define IDX_OFF   (TOK_TOTAL * NEXP)
#define LOSS_OFF  (IDX_OFF + TOK_TOTAL * 2)

// ws (floats): WH8 [65536] | WL8 [65536] | cntp [512*64] | rep_cnt | rep_list
#define WS_WL     65536
#define WS_CNTP   (2 * 65536)
#define WS_RCNT   (WS_CNTP + NBLK * NEXP)
#define WS_RLIST  (WS_RCNT + 1)

typedef __attribute__((ext_vector_type(8))) short short8_t;
typedef __attribute__((ext_vector_type(4))) float f32x4;

__device__ __forceinline__ short cvh(float f) {
    return __builtin_bit_cast(short, __float2bfloat16(f));
}
__device__ __forceinline__ short cvl(float f) {
    __hip_bfloat16 h = __float2bfloat16(f);
    return __builtin_bit_cast(short, __float2bfloat16(f - __bfloat162float(h)));
}

// async 16B/lane global->LDS: dest = wave-uniform base + lane*16, src per-lane
__device__ __forceinline__ void gload16(const void* gp, void* lp) {
    __builtin_amdgcn_global_load_lds(
        (const __attribute__((address_space(1))) void*)gp,
        (__attribute__((address_space(3))) void*)lp, 16, 0, 0);
}

// ---- K0: split-bf16 W table, k8-major: WH8[k8][e] = bf16hi(W[e][8k8..+7]) ----
__global__ __launch_bounds__(256, 1)
void build_wt(const float* __restrict__ W, short8_t* __restrict__ WH8,
              short8_t* __restrict__ WL8, int* __restrict__ rep_cnt)
{
    const int id = blockIdx.x * 256 + threadIdx.x;   // 64 blocks -> 16384 entries
    if (id == 0) *rep_cnt = 0;
    const int k8 = id & 255, e = id >> 8;
    float4 a = *(const float4*)(W + (long)e * D_MODEL + k8 * 8);
    float4 b = *(const float4*)(W + (long)e * D_MODEL + k8 * 8 + 4);
    short8_t h8, l8;
    h8[0]=cvh(a.x); h8[1]=cvh(a.y); h8[2]=cvh(a.z); h8[3]=cvh(a.w);
    h8[4]=cvh(b.x); h8[5]=cvh(b.y); h8[6]=cvh(b.z); h8[7]=cvh(b.w);
    l8[0]=cvl(a.x); l8[1]=cvl(a.y); l8[2]=cvl(a.z); l8[3]=cvl(a.w);
    l8[4]=cvl(b.x); l8[5]=cvl(b.y); l8[6]=cvl(b.z); l8[7]=cvl(b.w);
    WH8[k8 * NEXP + e] = h8;
    WL8[k8 * NEXP + e] = l8;
}

// ---- K1: gload_lds-staged MFMA GEMM + fused top-2/gates/flags/counts --------
__global__ __launch_bounds__(256, 2)
void router_gemm(const float* __restrict__ x,
                 const short8_t* __restrict__ WH8, const short8_t* __restrict__ WL8,
                 float* __restrict__ out, float* __restrict__ cntp,
                 int* __restrict__ rep_cnt, int* __restrict__ rep_list)
{
    __shared__ __align__(16) float    sxf[2][BM][KC];   // 16 KB, source-swizzled
    __shared__ __align__(16) short8_t swh[2][8][NEXP];  // 16 KB
    __shared__ __align__(16) short8_t swl[2][8][NEXP];  // 16 KB
    __shared__ float4 s_ig[BM];

    const int t = threadIdx.x;
    const int w = t >> 6, l = t & 63;
    const int tg = w >> 1, eg = w & 1;       // wave: tokens tg*16.., experts eg*32..
    const int lane16 = l & 15, kq = l >> 4;
    const long tok0 = (long)blockIdx.x * BM;
    const int arow = tg * 16 + lane16;

    f32x4 acc0 = (f32x4){0.f,0.f,0.f,0.f};  // experts eg*32 + 0..15
    f32x4 acc1 = (f32x4){0.f,0.f,0.f,0.f};  // experts eg*32 + 16..31

    // ---- staging: x swizzled-source (d4 = s4 ^ (r&15)), W linear ----
    auto STAGE = [&](int c, int buf) {
        #pragma unroll
        for (int j = 0; j < 2; ++j) {
            const int rbase = w * 8 + j * 4;
            const int r  = rbase + (l >> 4);
            const int s4 = (l & 15) ^ (r & 15);
            gload16(x + (tok0 + r) * D_MODEL + c * KC + s4 * 4, &sxf[buf][rbase][0]);
        }
        #pragma unroll
        for (int j = 0; j < 2; ++j) {
            const int k8 = w * 2 + j;
            gload16(WH8 + ((long)c * 8 + k8) * NEXP + l, &swh[buf][k8][0]);
            gload16(WL8 + ((long)c * 8 + k8) * NEXP + l, &swl[buf][k8][0]);
        }
    };

    auto COMPUTE = [&](int buf) {
        #pragma unroll
        for (int seg = 0; seg < 2; ++seg) {
            const int c4  = seg * 8 + kq * 2;
            f32x4 fa = *(const f32x4*)&sxf[buf][arow][((c4    ) ^ lane16) * 4];
            f32x4 fb = *(const f32x4*)&sxf[buf][arow][((c4 + 1) ^ lane16) * 4];
            short8_t ah, al;
            ah[0]=cvh(fa[0]); ah[1]=cvh(fa[1]); ah[2]=cvh(fa[2]); ah[3]=cvh(fa[3]);
            ah[4]=cvh(fb[0]); ah[5]=cvh(fb[1]); ah[6]=cvh(fb[2]); ah[7]=cvh(fb[3]);
            al[0]=cvl(fa[0]); al[1]=cvl(fa[1]); al[2]=cvl(fa[2]); al[3]=cvl(fa[3]);
            al[4]=cvl(fb[0]); al[5]=cvl(fb[1]); al[6]=cvl(fb[2]); al[7]=cvl(fb[3]);
            const int k8 = seg * 4 + kq;
            short8_t bh0 = swh[buf][k8][eg * 32 + lane16];
            short8_t bl0 = swl[buf][k8][eg * 32 + lane16];
            short8_t bh1 = swh[buf][k8][eg * 32 + 16 + lane16];
            short8_t bl1 = swl[buf][k8][eg * 32 + 16 + lane16];
            acc0 = __builtin_amdgcn_mfma_f32_16x16x32_bf16(ah, bl0, acc0, 0, 0, 0);
            acc0 = __builtin_amdgcn_mfma_f32_16x16x32_bf16(al, bh0, acc0, 0, 0, 0);
            acc0 = __builtin_amdgcn_mfma_f32_16x16x32_bf16(ah, bh0, acc0, 0, 0, 0);
            acc1 = __builtin_amdgcn_mfma_f32_16x16x32_bf16(ah, bl1, acc1, 0, 0, 0);
            acc1 = __builtin_amdgcn_mfma_f32_16x16x32_bf16(al, bh1, acc1, 0, 0, 0);
            acc1 = __builtin_amdgcn_mfma_f32_16x16x32_bf16(ah, bh1, acc1, 0, 0, 0);
        }
    };

    STAGE(0, 0);
    __syncthreads();                          // drains prologue loads

    for (int c = 0; c < NCH; ++c) {
        const int buf = c & 1;
        if (c + 1 < NCH) STAGE(c + 1, buf ^ 1);  // fire-and-forget, flies over COMPUTE
        COMPUTE(buf);
        __syncthreads();                      // vmcnt(0)+lgkmcnt(0)+barrier
    }

    // ---- logits -> LDS (alias sxf; safe after final barrier) ----
    float* Lg = (float*)&sxf[0][0][0];        // [32][68]
    {
        const int trow = tg * 16 + kq * 4;
        #pragma unroll
        for (int r = 0; r < 4; ++r) {
            Lg[(trow + r) * 68 + eg * 32 + lane16]      = acc0[r];
            Lg[(trow + r) * 68 + eg * 32 + 16 + lane16] = acc1[r];
        }
    }
    __syncthreads();

    // ---- top-3, idx, flags ----
    if (t < BM) {
        const float* lrow = Lg + t * 68;
        float b0 = -1e30f, b1 = -1e30f, b2 = -1e30f;
        int i0 = 0, i1 = 0;
        for (int e = 0; e < NEXP; ++e) {
            float v = lrow[e];
            if (v > b0)      { b2 = b1; b1 = b0; i1 = i0; b0 = v; i0 = e; }
            else if (v > b1) { b2 = b1; b1 = v; i1 = e; }
            else if (v > b2) { b2 = v; }
        }
        float ex = __expf(b1 - b0);
        float g0 = 1.f / (1.f + ex);
        long tok = tok0 + t;
        out[IDX_OFF + 2 * tok]     = (float)i0;
        out[IDX_OFF + 2 * tok + 1] = (float)i1;
        s_ig[t] = make_float4((float)i0, (float)i1, g0, ex * g0);
        if ((b0 - b1 < TAU) || (b1 - b2 < TAU)) {
            int p = atomicAdd(rep_cnt, 1);
            rep_list[p] = (int)tok;
        }
    }
    __syncthreads();

    // ---- dense gates: 8 lanes per token, 8 floats each ----
    {
        const int r8 = t >> 3, e0 = (t & 7) * 8;
        float4 gg = s_ig[r8];
        const int i0 = (int)gg.x, i1 = (int)gg.y;
        float v[8];
        #pragma unroll
        for (int j = 0; j < 8; ++j) {
            int e = e0 + j;
            v[j] = (e == i0) ? gg.z : ((e == i1) ? gg.w : 0.f);
        }
        float* orow = out + (tok0 + r8) * NEXP + e0;
        *(float4*)(orow)     = make_float4(v[0], v[1], v[2], v[3]);
        *(float4*)(orow + 4) = make_float4(v[4], v[5], v[6], v[7]);
    }

    // ---- per-block expert counts ----
    if (t < NEXP) {
        float cs = 0.f;
        for (int tt = 0; tt < BM; ++tt) {
            float4 gg = s_ig[tt];
            if ((int)gg.x == t) cs += gg.z;
            if ((int)gg.y == t) cs += gg.w;
        }
        cntp[blockIdx.x * NEXP + t] = cs;
    }
}

// -------- K2: fused tail: block 0 = loss; blocks 1.. = fp64 index repair ------
__global__ __launch_bounds__(256, 1)
void router_tail(const float* __restrict__ x, const float* __restrict__ W,
                 float* __restrict__ out, const float* __restrict__ cntp,
                 const int* __restrict__ rep_cnt, const int* __restrict__ rep_list)
{
    const int t = threadIdx.x;

    if (blockIdx.x == 0) {
        __shared__ double red[4][NEXP];
        const int e = t & 63, p = t >> 6;
        double s = 0.0;
        for (int b = 0; b < NBLK / 4; ++b)
            s += (double)cntp[(p * (NBLK / 4) + b) * NEXP + e];
        red[p][e] = s;
        __syncthreads();
        if (t == 0) {
            double sc[NEXP], tot = 0.0;
            for (int i = 0; i < NEXP; ++i) {
                sc[i] = red[0][i] + red[1][i] + red[2][i] + red[3][i];
                tot += sc[i];
            }
            double loss = 0.0;
            for (int i = 0; i < NEXP; ++i) {
                double d = sc[i] / tot * (double)NEXP - 1.0;
                loss += d * d;
            }
            out[LOSS_OFF] = (float)(loss / NEXP);
        }
        return;
    }

    __shared__ double red[4][NEXP];
    const int nf = *rep_cnt;
    const int e = t & 63, part = t >> 6;
    for (int i = (int)blockIdx.x - 1; i < nf; i += (int)gridDim.x - 1) {
        const long tok = rep_list[i];
        const float* xr = x + tok * D_MODEL;
        const float* wr = W + (long)e * D_MODEL;
        const int k0 = part * 512;
        double s = 0.0;
        for (int kk = 0; kk < 512; kk += 4) {
            float4 xv = *(const float4*)(xr + k0 + kk);
            float4 wv = *(const float4*)(wr + k0 + kk);
            s = fma((double)xv.x, (double)wv.x, s);
            s = fma((double)xv.y, (double)wv.y, s);
            s = fma((double)xv.z, (double)wv.z, s);
            s = fma((double)xv.w, (double)wv.w, s);
        }
        red[part][e] = s;
        __syncthreads();
        if (t == 0) {
            double best = -1e300, sec = -1e300;
            int bi = 0, si = 0;
            for (int ee = 0; ee < NEXP; ++ee) {
                double vv = red[0][ee] + red[1][ee] + red[2][ee] + red[3][ee];
                if (vv > best)     { sec = best; si = bi; best = vv; bi = ee; }
                else if (vv > sec) { sec = vv; si = ee; }
            }
            out[IDX_OFF + 2 * tok]     = (float)bi;
            out[IDX_OFF + 2 * tok + 1] = (float)si;
        }
        __syncthreads();
    }
}

extern "C" void kernel_launch(void* const* d_in, const int* in_sizes, int n_in,
                              void* d_out, int out_size, void* d_ws, size_t ws_size,
                              hipStream_t stream)
{
    const float* x = (const float*)d_in[0];
    const float* W = (const float*)d_in[1];
    float* out = (float*)d_out;
    float* ws  = (float*)d_ws;         // ~850 KB used
    short8_t* WH8 = (short8_t*)ws;
    short8_t* WL8 = (short8_t*)(ws + WS_WL);
    float* cntp = ws + WS_CNTP;
    int* rep_cnt  = (int*)(ws + WS_RCNT);
    int* rep_list = (int*)(ws + WS_RLIST);

    build_wt   <<<64, 256, 0, stream>>>(W, WH8, WL8, rep_cnt);
    router_gemm<<<NBLK, 256, 0, stream>>>(x, WH8, WL8, out, cntp, rep_cnt, rep_list);
    router_tail<<<257, 256, 0, stream>>>(x, W, out, cntp, rep_cnt, rep_list);
}